// Round 1
// baseline (1612.724 us; speedup 1.0000x reference)
//
#include <hip/hip_runtime.h>
#include <hip/hip_bf16.h>
#include <math.h>

#define NN 100000     // nodes
#define NE 800000     // edges per relation
#define FD 128        // feature dim

// ---------- float <-> ordered-uint encoding for atomic max on floats ----------
__device__ inline unsigned enc_f32(float f){
    unsigned u = __float_as_uint(f);
    return (u & 0x80000000u) ? ~u : (u | 0x80000000u);
}
__device__ inline float dec_f32(unsigned u){
    u = (u & 0x80000000u) ? (u ^ 0x80000000u) : ~u;
    return __uint_as_float(u);
}

// ---------- CSR build ----------
__global__ void k_hist(const int* __restrict__ dst, int* __restrict__ counts){
    int i = blockIdx.x * blockDim.x + threadIdx.x;
    if (i < NE) atomicAdd(&counts[dst[i]], 1);
}

#define SCAN_TILE 1024
__global__ void k_scan_partial(const int* __restrict__ counts, int n, int* __restrict__ partials){
    __shared__ int sm[256];
    int base = blockIdx.x * SCAN_TILE;
    int t = threadIdx.x;
    int s = 0;
    #pragma unroll
    for (int j = 0; j < 4; j++){
        int idx = base + t*4 + j;
        if (idx < n) s += counts[idx];
    }
    sm[t] = s; __syncthreads();
    for (int off = 128; off > 0; off >>= 1){
        if (t < off) sm[t] += sm[t+off];
        __syncthreads();
    }
    if (t == 0) partials[blockIdx.x] = sm[0];
}

__global__ void k_scan_partials_excl(int* partials, int nb){
    __shared__ int sm[256];
    int t = threadIdx.x;
    int v = (t < nb) ? partials[t] : 0;
    sm[t] = v; __syncthreads();
    for (int off = 1; off < 256; off <<= 1){
        int add = (t >= off) ? sm[t-off] : 0;
        __syncthreads();
        sm[t] += add;
        __syncthreads();
    }
    if (t < nb) partials[t] = sm[t] - v;   // exclusive
}

__global__ void k_scan_final(const int* __restrict__ counts, int n,
                             const int* __restrict__ partials, int* __restrict__ rowptr){
    __shared__ int sm[256];
    int base = blockIdx.x * SCAN_TILE;
    int t = threadIdx.x;
    int v[4]; int s = 0;
    #pragma unroll
    for (int j = 0; j < 4; j++){
        int idx = base + t*4 + j;
        v[j] = (idx < n) ? counts[idx] : 0;
        s += v[j];
    }
    sm[t] = s; __syncthreads();
    for (int off = 1; off < 256; off <<= 1){
        int add = (t >= off) ? sm[t-off] : 0;
        __syncthreads();
        sm[t] += add;
        __syncthreads();
    }
    int excl = sm[t] - s + partials[blockIdx.x];
    #pragma unroll
    for (int j = 0; j < 4; j++){
        int idx = base + t*4 + j;
        if (idx < n) rowptr[idx] = excl;
        excl += v[j];
    }
    if (blockIdx.x == 0 && t == 0) rowptr[n] = NE;
}

__global__ void k_scatter(const int* __restrict__ dst, int* __restrict__ cursor, int* __restrict__ col){
    int i = blockIdx.x * blockDim.x + threadIdx.x;
    if (i < NE){
        int p = atomicAdd(&cursor[dst[i]], 1);
        col[p] = i;
    }
}

// ---------- GEMM: out(N,128) = (relu?)(A(N,128)) @ W(128,128), fp32 ----------
template<bool RELU>
__global__ __launch_bounds__(256) void k_gemm(const float* __restrict__ A,
                                              const float* __restrict__ W,
                                              float* __restrict__ out){
    __shared__ float Ws[128*128];
    __shared__ float As[16*132];   // pad 132 to break bank aliasing
    int t = threadIdx.x;
    #pragma unroll
    for (int i = 0; i < 16; i++){
        int idx = t*4 + i*1024;
        *(float4*)&Ws[idx] = *(const float4*)&W[idx];
    }
    long row0 = (long)blockIdx.x * 16;
    #pragma unroll
    for (int i = 0; i < 2; i++){
        int idx = t*4 + i*1024;
        int r = idx >> 7, c = idx & 127;
        float4 a = *(const float4*)&A[(row0 + r)*FD + c];
        if (RELU){
            a.x = fmaxf(a.x, 0.f); a.y = fmaxf(a.y, 0.f);
            a.z = fmaxf(a.z, 0.f); a.w = fmaxf(a.w, 0.f);
        }
        *(float4*)&As[r*132 + c] = a;
    }
    __syncthreads();
    int r = t >> 4, c = t & 15;
    const float* arow = &As[r*132];
    float4 acc0 = make_float4(0,0,0,0), acc1 = make_float4(0,0,0,0);
    #pragma unroll 4
    for (int k = 0; k < 128; k++){
        float a = arow[k];
        float4 w0 = *(const float4*)&Ws[k*FD + c*4];
        float4 w1 = *(const float4*)&Ws[k*FD + 64 + c*4];
        acc0.x = fmaf(a, w0.x, acc0.x); acc0.y = fmaf(a, w0.y, acc0.y);
        acc0.z = fmaf(a, w0.z, acc0.z); acc0.w = fmaf(a, w0.w, acc0.w);
        acc1.x = fmaf(a, w1.x, acc1.x); acc1.y = fmaf(a, w1.y, acc1.y);
        acc1.z = fmaf(a, w1.z, acc1.z); acc1.w = fmaf(a, w1.w, acc1.w);
    }
    float* orow = &out[(row0 + r)*FD];
    *(float4*)&orow[c*4] = acc0;
    *(float4*)&orow[64 + c*4] = acc1;
}

// ---------- el/er: per-node attention-score reductions ----------
template<int H>
__global__ void k_eler(const float* __restrict__ feat, const float* __restrict__ al,
                       const float* __restrict__ ar, float* __restrict__ el,
                       float* __restrict__ er){
    int node = (blockIdx.x * blockDim.x + threadIdx.x) >> 6;
    int lane = threadIdx.x & 63;
    if (node >= NN) return;
    float f0 = feat[node*FD + lane];
    float f1 = feat[node*FD + 64 + lane];
    float pl0 = f0 * al[lane],      pl1 = f1 * al[64 + lane];
    float pr0 = f0 * ar[lane],      pr1 = f1 * ar[64 + lane];
    if (H == 1){ pl0 += pl1; pr0 += pr1; }
    #pragma unroll
    for (int off = 32; off > 0; off >>= 1){
        pl0 += __shfl_down(pl0, off);
        pr0 += __shfl_down(pr0, off);
        if (H == 2){
            pl1 += __shfl_down(pl1, off);
            pr1 += __shfl_down(pr1, off);
        }
    }
    if (lane == 0){
        if (H == 2){
            el[node*2]   = pl0; el[node*2+1] = pl1;
            er[node*2]   = pr0; er[node*2+1] = pr1;
        } else {
            el[node] = pl0; er[node] = pr0;
        }
    }
}

// ---------- edge passes ----------
template<int H>
__global__ void k_edge_max(const int* __restrict__ src, const int* __restrict__ dst,
                           const float* __restrict__ el, const float* __restrict__ er,
                           unsigned* __restrict__ menc){
    int i = blockIdx.x * blockDim.x + threadIdx.x;
    if (i >= NE) return;
    int s = src[i], d = dst[i];
    #pragma unroll
    for (int h = 0; h < H; h++){
        float e = el[s*H + h] + er[d*H + h];
        e = (e > 0.f) ? e : 0.2f * e;
        atomicMax(&menc[d*H + h], enc_f32(e));
    }
}

template<int H>
__global__ void k_edge_exp(const int* __restrict__ src, const int* __restrict__ dst,
                           const float* __restrict__ el, const float* __restrict__ er,
                           const unsigned* __restrict__ menc, float* __restrict__ ssum,
                           float* __restrict__ exv){
    int i = blockIdx.x * blockDim.x + threadIdx.x;
    if (i >= NE) return;
    int s = src[i], d = dst[i];
    #pragma unroll
    for (int h = 0; h < H; h++){
        float e = el[s*H + h] + er[d*H + h];
        e = (e > 0.f) ? e : 0.2f * e;
        float m = dec_f32(menc[d*H + h]);
        float ex = __expf(e - m);
        exv[i*H + h] = ex;
        atomicAdd(&ssum[d*H + h], ex);
    }
}

// ---------- aggregation: one wave per dst node ----------
template<int H>
__global__ void k_agg(const int* __restrict__ rowptr, const int* __restrict__ col,
                      const int* __restrict__ src, const float* __restrict__ exv,
                      const float* __restrict__ ssum, const float* __restrict__ feat,
                      const float* __restrict__ bias, float* __restrict__ out, int first){
    int node = (blockIdx.x * blockDim.x + threadIdx.x) >> 6;
    int lane = threadIdx.x & 63;
    if (node >= NN) return;
    int beg = rowptr[node], end = rowptr[node+1];
    float inv0 = 0.f, inv1 = 0.f;
    if (end > beg){
        inv0 = 1.0f / ssum[node*H];
        if (H == 2) inv1 = 1.0f / ssum[node*H + 1];
    }
    float acc0 = 0.f, acc1 = 0.f;
    for (int i = beg; i < end; i++){
        int e = col[i];
        int s = src[e];
        float a0 = exv[e*H] * inv0;
        float a1 = (H == 2) ? exv[e*H + 1] * inv1 : a0;
        acc0 += a0 * feat[s*FD + lane];
        acc1 += a1 * feat[s*FD + 64 + lane];
    }
    float v0 = 0.5f * (acc0 + bias[lane]);
    float v1 = 0.5f * (acc1 + bias[64 + lane]);
    if (first){
        out[node*FD + lane]      = v0;
        out[node*FD + 64 + lane] = v1;
    } else {
        out[node*FD + lane]      += v0;
        out[node*FD + 64 + lane] += v1;
    }
}

// ---------- launch ----------
extern "C" void kernel_launch(void* const* d_in, const int* in_sizes, int n_in,
                              void* d_out, int out_size, void* d_ws, size_t ws_size,
                              hipStream_t stream){
    const float* x   = (const float*)d_in[0];
    const float* W1  = (const float*)d_in[1];
    const float* al1 = (const float*)d_in[2];
    const float* ar1 = (const float*)d_in[3];
    const float* b1  = (const float*)d_in[4];
    const float* W2  = (const float*)d_in[5];
    const float* al2 = (const float*)d_in[6];
    const float* ar2 = (const float*)d_in[7];
    const float* b2  = (const float*)d_in[8];
    const int*   src = (const int*)d_in[9];
    const int*   dst = (const int*)d_in[10];
    float* out = (float*)d_out;

    // workspace carve-up
    size_t off = 0;
    auto carve = [&](size_t bytes) -> char* {
        char* p = (char*)d_ws + off;
        off += (bytes + 255) & ~(size_t)255;
        return p;
    };
    float*    feat    = (float*)   carve((size_t)NN * FD * 4);
    float*    h1      = (float*)   carve((size_t)NN * FD * 4);
    float*    el      = (float*)   carve((size_t)NN * 2 * 4);
    float*    er      = (float*)   carve((size_t)NN * 2 * 4);
    unsigned* menc    = (unsigned*)carve((size_t)NN * 2 * 4);
    float*    ssum    = (float*)   carve((size_t)NN * 2 * 4);
    float*    exv     = (float*)   carve((size_t)NE * 2 * 4);
    int*      rowptr0 = (int*)     carve((size_t)(NN + 1) * 4);
    int*      rowptr1 = (int*)     carve((size_t)(NN + 1) * 4);
    int*      col0    = (int*)     carve((size_t)NE * 4);
    int*      col1    = (int*)     carve((size_t)NE * 4);
    int*      counts  = (int*)     carve((size_t)NN * 4);
    int*      cursor  = (int*)     carve((size_t)NN * 4);
    int*      partials= (int*)     carve(1024);
    if (off > ws_size) return;  // workspace too small; validation will flag

    const int EB = (NE + 255) / 256;          // 3125
    const int NB = (NN + SCAN_TILE - 1) / SCAN_TILE;  // 98
    const int GB = NN / 16;                   // 6250
    const int WB = NN / 4;                    // 25000 (4 waves/block)

    int* rowptrs[2] = {rowptr0, rowptr1};
    int* cols[2]    = {col0, col1};

    // build CSR per relation (shared by both layers)
    for (int r = 0; r < 2; r++){
        const int* dstr = dst + (size_t)r * NE;
        hipMemsetAsync(counts, 0, (size_t)NN * 4, stream);
        k_hist<<<EB, 256, 0, stream>>>(dstr, counts);
        k_scan_partial<<<NB, 256, 0, stream>>>(counts, NN, partials);
        k_scan_partials_excl<<<1, 256, 0, stream>>>(partials, NB);
        k_scan_final<<<NB, 256, 0, stream>>>(counts, NN, partials, rowptrs[r]);
        hipMemcpyAsync(cursor, rowptrs[r], (size_t)NN * 4, hipMemcpyDeviceToDevice, stream);
        k_scatter<<<EB, 256, 0, stream>>>(dstr, cursor, cols[r]);
    }

    // layer 1: H=2, D=64
    for (int r = 0; r < 2; r++){
        const int* srcr = src + (size_t)r * NE;
        const int* dstr = dst + (size_t)r * NE;
        k_gemm<false><<<GB, 256, 0, stream>>>(x, W1 + (size_t)r * FD * FD, feat);
        k_eler<2><<<WB, 256, 0, stream>>>(feat, al1 + r*FD, ar1 + r*FD, el, er);
        hipMemsetAsync(menc, 0, (size_t)NN * 2 * 4, stream);
        hipMemsetAsync(ssum, 0, (size_t)NN * 2 * 4, stream);
        k_edge_max<2><<<EB, 256, 0, stream>>>(srcr, dstr, el, er, menc);
        k_edge_exp<2><<<EB, 256, 0, stream>>>(srcr, dstr, el, er, menc, ssum, exv);
        k_agg<2><<<WB, 256, 0, stream>>>(rowptrs[r], cols[r], srcr, exv, ssum, feat,
                                         b1 + r*FD, h1, r == 0);
    }

    // layer 2: H=1, D=128 (relu folded into GEMM A-load)
    for (int r = 0; r < 2; r++){
        const int* srcr = src + (size_t)r * NE;
        const int* dstr = dst + (size_t)r * NE;
        k_gemm<true><<<GB, 256, 0, stream>>>(h1, W2 + (size_t)r * FD * FD, feat);
        k_eler<1><<<WB, 256, 0, stream>>>(feat, al2 + r*FD, ar2 + r*FD, el, er);
        hipMemsetAsync(menc, 0, (size_t)NN * 4, stream);
        hipMemsetAsync(ssum, 0, (size_t)NN * 4, stream);
        k_edge_max<1><<<EB, 256, 0, stream>>>(srcr, dstr, el, er, menc);
        k_edge_exp<1><<<EB, 256, 0, stream>>>(srcr, dstr, el, er, menc, ssum, exv);
        k_agg<1><<<WB, 256, 0, stream>>>(rowptrs[r], cols[r], srcr, exv, ssum, feat,
                                         b2 + r*FD, out, r == 0);
    }
}

// Round 2
// 867.887 us; speedup vs baseline: 1.8582x; 1.8582x over previous
//
#include <hip/hip_runtime.h>
#include <hip/hip_bf16.h>
#include <math.h>

#define NN 100000     // nodes
#define NE 800000     // edges per relation
#define FD 128        // feature dim

// ---------- CSR build ----------
__global__ void k_hist(const int* __restrict__ dst, int* __restrict__ counts){
    int i = blockIdx.x * blockDim.x + threadIdx.x;
    if (i < NE) atomicAdd(&counts[dst[i]], 1);
}

#define SCAN_TILE 1024
__global__ void k_scan_partial(const int* __restrict__ counts, int n, int* __restrict__ partials){
    __shared__ int sm[256];
    int base = blockIdx.x * SCAN_TILE;
    int t = threadIdx.x;
    int s = 0;
    #pragma unroll
    for (int j = 0; j < 4; j++){
        int idx = base + t*4 + j;
        if (idx < n) s += counts[idx];
    }
    sm[t] = s; __syncthreads();
    for (int off = 128; off > 0; off >>= 1){
        if (t < off) sm[t] += sm[t+off];
        __syncthreads();
    }
    if (t == 0) partials[blockIdx.x] = sm[0];
}

__global__ void k_scan_partials_excl(int* partials, int nb){
    __shared__ int sm[256];
    int t = threadIdx.x;
    int v = (t < nb) ? partials[t] : 0;
    sm[t] = v; __syncthreads();
    for (int off = 1; off < 256; off <<= 1){
        int add = (t >= off) ? sm[t-off] : 0;
        __syncthreads();
        sm[t] += add;
        __syncthreads();
    }
    if (t < nb) partials[t] = sm[t] - v;   // exclusive
}

__global__ void k_scan_final(const int* __restrict__ counts, int n,
                             const int* __restrict__ partials, int* __restrict__ rowptr){
    __shared__ int sm[256];
    int base = blockIdx.x * SCAN_TILE;
    int t = threadIdx.x;
    int v[4]; int s = 0;
    #pragma unroll
    for (int j = 0; j < 4; j++){
        int idx = base + t*4 + j;
        v[j] = (idx < n) ? counts[idx] : 0;
        s += v[j];
    }
    sm[t] = s; __syncthreads();
    for (int off = 1; off < 256; off <<= 1){
        int add = (t >= off) ? sm[t-off] : 0;
        __syncthreads();
        sm[t] += add;
        __syncthreads();
    }
    int excl = sm[t] - s + partials[blockIdx.x];
    #pragma unroll
    for (int j = 0; j < 4; j++){
        int idx = base + t*4 + j;
        if (idx < n) rowptr[idx] = excl;
        excl += v[j];
    }
    if (blockIdx.x == 0 && t == 0) rowptr[n] = NE;
}

// store SOURCE NODE ID directly (not edge id) -> removes one indirection in agg
__global__ void k_scatter(const int* __restrict__ dst, const int* __restrict__ src,
                          int* __restrict__ cursor, int* __restrict__ colsrc){
    int i = blockIdx.x * blockDim.x + threadIdx.x;
    if (i < NE){
        int p = atomicAdd(&cursor[dst[i]], 1);
        colsrc[p] = src[i];
    }
}

// ---------- helpers ----------
__device__ inline float dot4(float4 a, float4 b){
    return fmaf(a.x, b.x, fmaf(a.y, b.y, fmaf(a.z, b.z, a.w * b.w)));
}
__device__ inline float red16(float v){
    v += __shfl_xor(v, 1);
    v += __shfl_xor(v, 2);
    v += __shfl_xor(v, 4);
    v += __shfl_xor(v, 8);
    return v;
}

// ---------- GEMM + fused el/er epilogue ----------
// feat(N,128) = (relu?)(A(N,128)) @ W(128,128); el/er = head-wise dot with al/ar.
// 64-row tile, 256 threads, thread = 4 rows x 8 cols. LDS ~98KB -> 1 block/CU.
template<int H, bool RELU>
__global__ __launch_bounds__(256) void k_gemm(const float* __restrict__ A,
                                              const float* __restrict__ W,
                                              const float* __restrict__ al,
                                              const float* __restrict__ ar,
                                              float* __restrict__ feat,
                                              float* __restrict__ el,
                                              float* __restrict__ er){
    __shared__ float Ws[128*128];
    __shared__ float As[64*132];   // padded row stride (broadcast reads, coalesced writes)
    int t = threadIdx.x;
    #pragma unroll
    for (int i = 0; i < 16; i++){
        int idx = t*4 + i*1024;
        *(float4*)&Ws[idx] = *(const float4*)&W[idx];
    }
    long row0 = (long)blockIdx.x * 64;
    #pragma unroll
    for (int i = 0; i < 8; i++){
        int idx = t*4 + i*1024;
        int r = idx >> 7, c = idx & 127;
        float4 a = make_float4(0.f, 0.f, 0.f, 0.f);
        if (row0 + r < NN){
            a = *(const float4*)&A[(row0 + r)*FD + c];
            if (RELU){
                a.x = fmaxf(a.x, 0.f); a.y = fmaxf(a.y, 0.f);
                a.z = fmaxf(a.z, 0.f); a.w = fmaxf(a.w, 0.f);
            }
        }
        *(float4*)&As[r*132 + c] = a;
    }
    __syncthreads();
    int g = t >> 4, c = t & 15;
    int r0 = g * 4;
    float4 acc[4][2];
    #pragma unroll
    for (int i = 0; i < 4; i++){
        acc[i][0] = make_float4(0.f,0.f,0.f,0.f);
        acc[i][1] = make_float4(0.f,0.f,0.f,0.f);
    }
    #pragma unroll 4
    for (int k = 0; k < 128; k++){
        float4 w0 = *(const float4*)&Ws[k*FD + c*4];
        float4 w1 = *(const float4*)&Ws[k*FD + 64 + c*4];
        #pragma unroll
        for (int i = 0; i < 4; i++){
            float a = As[(r0+i)*132 + k];
            acc[i][0].x = fmaf(a, w0.x, acc[i][0].x);
            acc[i][0].y = fmaf(a, w0.y, acc[i][0].y);
            acc[i][0].z = fmaf(a, w0.z, acc[i][0].z);
            acc[i][0].w = fmaf(a, w0.w, acc[i][0].w);
            acc[i][1].x = fmaf(a, w1.x, acc[i][1].x);
            acc[i][1].y = fmaf(a, w1.y, acc[i][1].y);
            acc[i][1].z = fmaf(a, w1.z, acc[i][1].z);
            acc[i][1].w = fmaf(a, w1.w, acc[i][1].w);
        }
    }
    // epilogue: feat stores + fused el/er
    float4 alv0 = *(const float4*)&al[c*4];
    float4 alv1 = *(const float4*)&al[64 + c*4];
    float4 arv0 = *(const float4*)&ar[c*4];
    float4 arv1 = *(const float4*)&ar[64 + c*4];
    #pragma unroll
    for (int i = 0; i < 4; i++){
        long row = row0 + r0 + i;
        if (row < NN){
            *(float4*)&feat[row*FD + c*4]      = acc[i][0];
            *(float4*)&feat[row*FD + 64 + c*4] = acc[i][1];
        }
        if (H == 2){
            float pl0 = red16(dot4(acc[i][0], alv0));
            float pl1 = red16(dot4(acc[i][1], alv1));
            float pr0 = red16(dot4(acc[i][0], arv0));
            float pr1 = red16(dot4(acc[i][1], arv1));
            if (c == 0 && row < NN){
                el[row*2]   = pl0; el[row*2+1] = pl1;
                er[row*2]   = pr0; er[row*2+1] = pr1;
            }
        } else {
            float pl = red16(dot4(acc[i][0], alv0) + dot4(acc[i][1], alv1));
            float pr = red16(dot4(acc[i][0], arv0) + dot4(acc[i][1], arv1));
            if (c == 0 && row < NN){
                el[row] = pl; er[row] = pr;
            }
        }
    }
}

// ---------- aggregation with inline softmax: one wave per dst node ----------
// lane holds feat cols {2*lane, 2*lane+1}; H=2: lanes<32 = head0, lanes>=32 = head1.
template<int H>
__global__ void k_agg(const int* __restrict__ rowptr, const int* __restrict__ colsrc,
                      const float* __restrict__ el, const float* __restrict__ er,
                      const float* __restrict__ feat, const float* __restrict__ bias,
                      float* __restrict__ out, int first){
    int node = (blockIdx.x * blockDim.x + threadIdx.x) >> 6;
    int lane = threadIdx.x & 63;
    if (node >= NN) return;
    int beg = rowptr[node], end = rowptr[node+1];
    float er0 = er[node*H];
    float er1 = (H == 2) ? er[node*H + 1] : 0.f;
    float s0 = 0.f, s1 = 0.f;
    float accx = 0.f, accy = 0.f;
    for (int base = beg; base < end; base += 64){
        bool active = (base + lane) < end;
        int sv = active ? colsrc[base + lane] : 0;
        float a0 = 0.f, a1 = 0.f;
        if (active){
            if (H == 2){
                float2 e2 = *(const float2*)&el[sv*2];
                float e0 = e2.x + er0, e1 = e2.y + er1;
                e0 = (e0 > 0.f) ? e0 : 0.2f*e0;
                e1 = (e1 > 0.f) ? e1 : 0.2f*e1;
                a0 = __expf(e0); a1 = __expf(e1);
            } else {
                float e0 = el[sv] + er0;
                e0 = (e0 > 0.f) ? e0 : 0.2f*e0;
                a0 = __expf(e0);
            }
        }
        s0 += a0;
        if (H == 2) s1 += a1;
        int n = min(64, end - base);
        for (int j = 0; j < n; j++){
            int sj = __shfl(sv, j);
            float w0 = __shfl(a0, j);
            float w;
            if (H == 2){
                float w1 = __shfl(a1, j);
                w = (lane < 32) ? w0 : w1;
            } else {
                w = w0;
            }
            float2 f = *(const float2*)&feat[(size_t)sj*FD + lane*2];
            accx = fmaf(w, f.x, accx);
            accy = fmaf(w, f.y, accy);
        }
    }
    #pragma unroll
    for (int off = 32; off > 0; off >>= 1){
        s0 += __shfl_xor(s0, off);
        if (H == 2) s1 += __shfl_xor(s1, off);
    }
    float inv0 = (end > beg) ? 1.f/s0 : 0.f;
    float inv1 = (H == 2 && end > beg) ? 1.f/s1 : 0.f;
    float inv = (H == 2) ? ((lane < 32) ? inv0 : inv1) : inv0;
    float2 b = *(const float2*)&bias[lane*2];
    float vx = 0.5f*(accx*inv + b.x);
    float vy = 0.5f*(accy*inv + b.y);
    float* o = &out[(size_t)node*FD + lane*2];
    if (first){ o[0] = vx; o[1] = vy; }
    else      { o[0] += vx; o[1] += vy; }
}

// ---------- launch ----------
extern "C" void kernel_launch(void* const* d_in, const int* in_sizes, int n_in,
                              void* d_out, int out_size, void* d_ws, size_t ws_size,
                              hipStream_t stream){
    const float* x   = (const float*)d_in[0];
    const float* W1  = (const float*)d_in[1];
    const float* al1 = (const float*)d_in[2];
    const float* ar1 = (const float*)d_in[3];
    const float* b1  = (const float*)d_in[4];
    const float* W2  = (const float*)d_in[5];
    const float* al2 = (const float*)d_in[6];
    const float* ar2 = (const float*)d_in[7];
    const float* b2  = (const float*)d_in[8];
    const int*   src = (const int*)d_in[9];
    const int*   dst = (const int*)d_in[10];
    float* out = (float*)d_out;

    size_t off = 0;
    auto carve = [&](size_t bytes) -> char* {
        char* p = (char*)d_ws + off;
        off += (bytes + 255) & ~(size_t)255;
        return p;
    };
    float* feat     = (float*)carve((size_t)NN * FD * 4);
    float* h1       = (float*)carve((size_t)NN * FD * 4);
    float* el       = (float*)carve((size_t)NN * 2 * 4);
    float* er       = (float*)carve((size_t)NN * 2 * 4);
    int*   rowptr0  = (int*)  carve((size_t)(NN + 1) * 4);
    int*   rowptr1  = (int*)  carve((size_t)(NN + 1) * 4);
    int*   colsrc0  = (int*)  carve((size_t)NE * 4);
    int*   colsrc1  = (int*)  carve((size_t)NE * 4);
    int*   counts   = (int*)  carve((size_t)NN * 4);
    int*   cursor   = (int*)  carve((size_t)NN * 4);
    int*   partials = (int*)  carve(1024);
    if (off > ws_size) return;

    const int EB = (NE + 255) / 256;
    const int NB = (NN + SCAN_TILE - 1) / SCAN_TILE;
    const int GB = (NN + 63) / 64;
    const int WB = NN / 4;   // 4 waves/block, 1 wave per node

    int* rowptrs[2] = {rowptr0, rowptr1};
    int* colsrcs[2] = {colsrc0, colsrc1};

    // build CSR per relation (shared by both layers); adjacency stores src ids
    for (int r = 0; r < 2; r++){
        const int* dstr = dst + (size_t)r * NE;
        const int* srcr = src + (size_t)r * NE;
        hipMemsetAsync(counts, 0, (size_t)NN * 4, stream);
        k_hist<<<EB, 256, 0, stream>>>(dstr, counts);
        k_scan_partial<<<NB, 256, 0, stream>>>(counts, NN, partials);
        k_scan_partials_excl<<<1, 256, 0, stream>>>(partials, NB);
        k_scan_final<<<NB, 256, 0, stream>>>(counts, NN, partials, rowptrs[r]);
        hipMemcpyAsync(cursor, rowptrs[r], (size_t)NN * 4, hipMemcpyDeviceToDevice, stream);
        k_scatter<<<EB, 256, 0, stream>>>(dstr, srcr, cursor, colsrcs[r]);
    }

    // layer 1: H=2, D=64
    for (int r = 0; r < 2; r++){
        k_gemm<2, false><<<GB, 256, 0, stream>>>(x, W1 + (size_t)r * FD * FD,
                                                 al1 + r*FD, ar1 + r*FD, feat, el, er);
        k_agg<2><<<WB, 256, 0, stream>>>(rowptrs[r], colsrcs[r], el, er, feat,
                                         b1 + r*FD, h1, r == 0);
    }

    // layer 2: H=1, D=128 (relu folded into GEMM A-load)
    for (int r = 0; r < 2; r++){
        k_gemm<1, true><<<GB, 256, 0, stream>>>(h1, W2 + (size_t)r * FD * FD,
                                                al2 + r*FD, ar2 + r*FD, feat, el, er);
        k_agg<1><<<WB, 256, 0, stream>>>(rowptrs[r], colsrcs[r], el, er, feat,
                                         b2 + r*FD, out, r == 0);
    }
}

// Round 3
// 730.608 us; speedup vs baseline: 2.2074x; 1.1879x over previous
//
#include <hip/hip_runtime.h>
#include <hip/hip_bf16.h>
#include <math.h>

#define NN 100000     // nodes
#define NE 800000     // edges per relation
#define FD 128        // feature dim

// ---------- CSR build ----------
__global__ void k_hist(const int* __restrict__ dst, int* __restrict__ counts){
    int i = blockIdx.x * blockDim.x + threadIdx.x;
    if (i < NE) atomicAdd(&counts[dst[i]], 1);
}

#define SCAN_TILE 1024
__global__ void k_scan_partial(const int* __restrict__ counts, int n, int* __restrict__ partials){
    __shared__ int sm[256];
    int base = blockIdx.x * SCAN_TILE;
    int t = threadIdx.x;
    int s = 0;
    #pragma unroll
    for (int j = 0; j < 4; j++){
        int idx = base + t*4 + j;
        if (idx < n) s += counts[idx];
    }
    sm[t] = s; __syncthreads();
    for (int off = 128; off > 0; off >>= 1){
        if (t < off) sm[t] += sm[t+off];
        __syncthreads();
    }
    if (t == 0) partials[blockIdx.x] = sm[0];
}

__global__ void k_scan_partials_excl(int* partials, int nb){
    __shared__ int sm[256];
    int t = threadIdx.x;
    int v = (t < nb) ? partials[t] : 0;
    sm[t] = v; __syncthreads();
    for (int off = 1; off < 256; off <<= 1){
        int add = (t >= off) ? sm[t-off] : 0;
        __syncthreads();
        sm[t] += add;
        __syncthreads();
    }
    if (t < nb) partials[t] = sm[t] - v;   // exclusive
}

__global__ void k_scan_final(const int* __restrict__ counts, int n,
                             const int* __restrict__ partials, int* __restrict__ rowptr){
    __shared__ int sm[256];
    int base = blockIdx.x * SCAN_TILE;
    int t = threadIdx.x;
    int v[4]; int s = 0;
    #pragma unroll
    for (int j = 0; j < 4; j++){
        int idx = base + t*4 + j;
        v[j] = (idx < n) ? counts[idx] : 0;
        s += v[j];
    }
    sm[t] = s; __syncthreads();
    for (int off = 1; off < 256; off <<= 1){
        int add = (t >= off) ? sm[t-off] : 0;
        __syncthreads();
        sm[t] += add;
        __syncthreads();
    }
    int excl = sm[t] - s + partials[blockIdx.x];
    #pragma unroll
    for (int j = 0; j < 4; j++){
        int idx = base + t*4 + j;
        if (idx < n) rowptr[idx] = excl;
        excl += v[j];
    }
    if (blockIdx.x == 0 && t == 0) rowptr[n] = NE;
}

// store SOURCE NODE ID directly (not edge id) -> removes one indirection in agg
__global__ void k_scatter(const int* __restrict__ dst, const int* __restrict__ src,
                          int* __restrict__ cursor, int* __restrict__ colsrc){
    int i = blockIdx.x * blockDim.x + threadIdx.x;
    if (i < NE){
        int p = atomicAdd(&cursor[dst[i]], 1);
        colsrc[p] = src[i];
    }
}

// ---------- helpers ----------
__device__ inline float dot4(float4 a, float4 b){
    return fmaf(a.x, b.x, fmaf(a.y, b.y, fmaf(a.z, b.z, a.w * b.w)));
}
__device__ inline float red16(float v){
    v += __shfl_xor(v, 1);
    v += __shfl_xor(v, 2);
    v += __shfl_xor(v, 4);
    v += __shfl_xor(v, 8);
    return v;
}

// ---------- GEMM + fused el/er epilogue, K-chunked for occupancy ----------
// feat(N,128) = (relu?)(A(N,128)) @ W(128,128); el/er = head-wise dot with al/ar.
// 64-row tile, 256 threads, thread = 4 rows x 8 cols. K streamed in 32-chunks:
// LDS = 16KB (W chunk) + 9KB (A chunk, stride 36 keeps 16B align + 2-way-free banks)
// = 25KB -> up to 6 blocks/CU by LDS; VGPR-limited ~4-5 -> occupancy ~50%.
template<int H, bool RELU>
__global__ __launch_bounds__(256) void k_gemm(const float* __restrict__ A,
                                              const float* __restrict__ W,
                                              const float* __restrict__ al,
                                              const float* __restrict__ ar,
                                              float* __restrict__ feat,
                                              float* __restrict__ el,
                                              float* __restrict__ er){
    __shared__ float Ws[32*128];   // 16 KB: K-chunk of W, layout [k][n]
    __shared__ float As[64*36];    // 9 KB: A chunk, row stride 36 (144B, 16B-aligned)
    int t = threadIdx.x;
    long row0 = (long)blockIdx.x * 64;
    int g = t >> 4, c = t & 15;
    int r0 = g * 4;
    int lr = t >> 3, lc = (t & 7) * 4;   // A-chunk load coords: 8 threads/row
    float4 acc[4][2];
    #pragma unroll
    for (int i = 0; i < 4; i++){
        acc[i][0] = make_float4(0.f,0.f,0.f,0.f);
        acc[i][1] = make_float4(0.f,0.f,0.f,0.f);
    }
    for (int k0 = 0; k0 < 128; k0 += 32){
        __syncthreads();   // previous chunk's LDS reads done
        #pragma unroll
        for (int i = 0; i < 4; i++){
            int idx = t*4 + i*1024;
            *(float4*)&Ws[idx] = *(const float4*)&W[k0*FD + idx];
        }
        #pragma unroll
        for (int i = 0; i < 2; i++){
            int r = lr + i*32;
            float4 a = make_float4(0.f, 0.f, 0.f, 0.f);
            if (row0 + r < NN){
                a = *(const float4*)&A[(row0 + r)*FD + k0 + lc];
                if (RELU){
                    a.x = fmaxf(a.x, 0.f); a.y = fmaxf(a.y, 0.f);
                    a.z = fmaxf(a.z, 0.f); a.w = fmaxf(a.w, 0.f);
                }
            }
            *(float4*)&As[r*36 + lc] = a;
        }
        __syncthreads();
        #pragma unroll 4
        for (int k = 0; k < 32; k++){
            float4 w0 = *(const float4*)&Ws[k*FD + c*4];
            float4 w1 = *(const float4*)&Ws[k*FD + 64 + c*4];
            #pragma unroll
            for (int i = 0; i < 4; i++){
                float a = As[(r0+i)*36 + k];
                acc[i][0].x = fmaf(a, w0.x, acc[i][0].x);
                acc[i][0].y = fmaf(a, w0.y, acc[i][0].y);
                acc[i][0].z = fmaf(a, w0.z, acc[i][0].z);
                acc[i][0].w = fmaf(a, w0.w, acc[i][0].w);
                acc[i][1].x = fmaf(a, w1.x, acc[i][1].x);
                acc[i][1].y = fmaf(a, w1.y, acc[i][1].y);
                acc[i][1].z = fmaf(a, w1.z, acc[i][1].z);
                acc[i][1].w = fmaf(a, w1.w, acc[i][1].w);
            }
        }
    }
    // epilogue: feat stores + fused el/er
    float4 alv0 = *(const float4*)&al[c*4];
    float4 alv1 = *(const float4*)&al[64 + c*4];
    float4 arv0 = *(const float4*)&ar[c*4];
    float4 arv1 = *(const float4*)&ar[64 + c*4];
    #pragma unroll
    for (int i = 0; i < 4; i++){
        long row = row0 + r0 + i;
        if (row < NN){
            *(float4*)&feat[row*FD + c*4]      = acc[i][0];
            *(float4*)&feat[row*FD + 64 + c*4] = acc[i][1];
        }
        if (H == 2){
            float pl0 = red16(dot4(acc[i][0], alv0));
            float pl1 = red16(dot4(acc[i][1], alv1));
            float pr0 = red16(dot4(acc[i][0], arv0));
            float pr1 = red16(dot4(acc[i][1], arv1));
            if (c == 0 && row < NN){
                el[row*2]   = pl0; el[row*2+1] = pl1;
                er[row*2]   = pr0; er[row*2+1] = pr1;
            }
        } else {
            float pl = red16(dot4(acc[i][0], alv0) + dot4(acc[i][1], alv1));
            float pr = red16(dot4(acc[i][0], arv0) + dot4(acc[i][1], arv1));
            if (c == 0 && row < NN){
                el[row] = pl; er[row] = pr;
            }
        }
    }
}

// ---------- aggregation with inline softmax: one wave per dst node ----------
// lane holds feat cols {2*lane, 2*lane+1}; H=2: lanes<32 = head0, lanes>=32 = head1.
template<int H>
__global__ void k_agg(const int* __restrict__ rowptr, const int* __restrict__ colsrc,
                      const float* __restrict__ el, const float* __restrict__ er,
                      const float* __restrict__ feat, const float* __restrict__ bias,
                      float* __restrict__ out, int first){
    int node = (blockIdx.x * blockDim.x + threadIdx.x) >> 6;
    int lane = threadIdx.x & 63;
    if (node >= NN) return;
    int beg = rowptr[node], end = rowptr[node+1];
    float er0 = er[node*H];
    float er1 = (H == 2) ? er[node*H + 1] : 0.f;
    float s0 = 0.f, s1 = 0.f;
    float accx = 0.f, accy = 0.f;
    for (int base = beg; base < end; base += 64){
        bool active = (base + lane) < end;
        int sv = active ? colsrc[base + lane] : 0;
        float a0 = 0.f, a1 = 0.f;
        if (active){
            if (H == 2){
                float2 e2 = *(const float2*)&el[sv*2];
                float e0 = e2.x + er0, e1 = e2.y + er1;
                e0 = (e0 > 0.f) ? e0 : 0.2f*e0;
                e1 = (e1 > 0.f) ? e1 : 0.2f*e1;
                a0 = __expf(e0); a1 = __expf(e1);
            } else {
                float e0 = el[sv] + er0;
                e0 = (e0 > 0.f) ? e0 : 0.2f*e0;
                a0 = __expf(e0);
            }
        }
        s0 += a0;
        if (H == 2) s1 += a1;
        int n = min(64, end - base);
        for (int j = 0; j < n; j++){
            int sj = __shfl(sv, j);
            float w0 = __shfl(a0, j);
            float w;
            if (H == 2){
                float w1 = __shfl(a1, j);
                w = (lane < 32) ? w0 : w1;
            } else {
                w = w0;
            }
            float2 f = *(const float2*)&feat[(size_t)sj*FD + lane*2];
            accx = fmaf(w, f.x, accx);
            accy = fmaf(w, f.y, accy);
        }
    }
    #pragma unroll
    for (int off = 32; off > 0; off >>= 1){
        s0 += __shfl_xor(s0, off);
        if (H == 2) s1 += __shfl_xor(s1, off);
    }
    float inv0 = (end > beg) ? 1.f/s0 : 0.f;
    float inv1 = (H == 2 && end > beg) ? 1.f/s1 : 0.f;
    float inv = (H == 2) ? ((lane < 32) ? inv0 : inv1) : inv0;
    float2 b = *(const float2*)&bias[lane*2];
    float vx = 0.5f*(accx*inv + b.x);
    float vy = 0.5f*(accy*inv + b.y);
    float* o = &out[(size_t)node*FD + lane*2];
    if (first){ o[0] = vx; o[1] = vy; }
    else      { o[0] += vx; o[1] += vy; }
}

// ---------- launch ----------
extern "C" void kernel_launch(void* const* d_in, const int* in_sizes, int n_in,
                              void* d_out, int out_size, void* d_ws, size_t ws_size,
                              hipStream_t stream){
    const float* x   = (const float*)d_in[0];
    const float* W1  = (const float*)d_in[1];
    const float* al1 = (const float*)d_in[2];
    const float* ar1 = (const float*)d_in[3];
    const float* b1  = (const float*)d_in[4];
    const float* W2  = (const float*)d_in[5];
    const float* al2 = (const float*)d_in[6];
    const float* ar2 = (const float*)d_in[7];
    const float* b2  = (const float*)d_in[8];
    const int*   src = (const int*)d_in[9];
    const int*   dst = (const int*)d_in[10];
    float* out = (float*)d_out;

    size_t off = 0;
    auto carve = [&](size_t bytes) -> char* {
        char* p = (char*)d_ws + off;
        off += (bytes + 255) & ~(size_t)255;
        return p;
    };
    float* feat     = (float*)carve((size_t)NN * FD * 4);
    float* h1       = (float*)carve((size_t)NN * FD * 4);
    float* el       = (float*)carve((size_t)NN * 2 * 4);
    float* er       = (float*)carve((size_t)NN * 2 * 4);
    int*   rowptr0  = (int*)  carve((size_t)(NN + 1) * 4);
    int*   rowptr1  = (int*)  carve((size_t)(NN + 1) * 4);
    int*   colsrc0  = (int*)  carve((size_t)NE * 4);
    int*   colsrc1  = (int*)  carve((size_t)NE * 4);
    int*   counts   = (int*)  carve((size_t)NN * 4);
    int*   cursor   = (int*)  carve((size_t)NN * 4);
    int*   partials = (int*)  carve(1024);
    if (off > ws_size) return;

    const int EB = (NE + 255) / 256;
    const int NB = (NN + SCAN_TILE - 1) / SCAN_TILE;
    const int GB = (NN + 63) / 64;
    const int WB = NN / 4;   // 4 waves/block, 1 wave per node

    int* rowptrs[2] = {rowptr0, rowptr1};
    int* colsrcs[2] = {colsrc0, colsrc1};

    // build CSR per relation (shared by both layers); adjacency stores src ids
    for (int r = 0; r < 2; r++){
        const int* dstr = dst + (size_t)r * NE;
        const int* srcr = src + (size_t)r * NE;
        hipMemsetAsync(counts, 0, (size_t)NN * 4, stream);
        k_hist<<<EB, 256, 0, stream>>>(dstr, counts);
        k_scan_partial<<<NB, 256, 0, stream>>>(counts, NN, partials);
        k_scan_partials_excl<<<1, 256, 0, stream>>>(partials, NB);
        k_scan_final<<<NB, 256, 0, stream>>>(counts, NN, partials, rowptrs[r]);
        hipMemcpyAsync(cursor, rowptrs[r], (size_t)NN * 4, hipMemcpyDeviceToDevice, stream);
        k_scatter<<<EB, 256, 0, stream>>>(dstr, srcr, cursor, colsrcs[r]);
    }

    // layer 1: H=2, D=64
    for (int r = 0; r < 2; r++){
        k_gemm<2, false><<<GB, 256, 0, stream>>>(x, W1 + (size_t)r * FD * FD,
                                                 al1 + r*FD, ar1 + r*FD, feat, el, er);
        k_agg<2><<<WB, 256, 0, stream>>>(rowptrs[r], colsrcs[r], el, er, feat,
                                         b1 + r*FD, h1, r == 0);
    }

    // layer 2: H=1, D=128 (relu folded into GEMM A-load)
    for (int r = 0; r < 2; r++){
        k_gemm<1, true><<<GB, 256, 0, stream>>>(h1, W2 + (size_t)r * FD * FD,
                                                al2 + r*FD, ar2 + r*FD, feat, el, er);
        k_agg<1><<<WB, 256, 0, stream>>>(rowptrs[r], colsrcs[r], el, er, feat,
                                         b2 + r*FD, out, r == 0);
    }
}

// Round 4
// 653.236 us; speedup vs baseline: 2.4688x; 1.1184x over previous
//
#include <hip/hip_runtime.h>
#include <hip/hip_bf16.h>
#include <math.h>

#define NN 100000     // nodes
#define NE 800000     // edges per relation
#define FD 128        // feature dim

typedef unsigned short ushort_t;

// ---------- bf16 pack helpers (round-to-nearest-even) ----------
__device__ inline unsigned f2bf(float f){
    unsigned u = __float_as_uint(f);
    return (u + 0x7fffu + ((u >> 16) & 1u)) >> 16;
}
__device__ inline unsigned pk(float a, float b){
    return f2bf(a) | (f2bf(b) << 16);
}

// ---------- CSR build ----------
__global__ void k_hist(const int* __restrict__ dst, int* __restrict__ counts){
    int i = blockIdx.x * blockDim.x + threadIdx.x;
    if (i < NE) atomicAdd(&counts[dst[i]], 1);
}

#define SCAN_TILE 1024
__global__ void k_scan_partial(const int* __restrict__ counts, int n, int* __restrict__ partials){
    __shared__ int sm[256];
    int base = blockIdx.x * SCAN_TILE;
    int t = threadIdx.x;
    int s = 0;
    #pragma unroll
    for (int j = 0; j < 4; j++){
        int idx = base + t*4 + j;
        if (idx < n) s += counts[idx];
    }
    sm[t] = s; __syncthreads();
    for (int off = 128; off > 0; off >>= 1){
        if (t < off) sm[t] += sm[t+off];
        __syncthreads();
    }
    if (t == 0) partials[blockIdx.x] = sm[0];
}

__global__ void k_scan_partials_excl(int* partials, int nb){
    __shared__ int sm[256];
    int t = threadIdx.x;
    int v = (t < nb) ? partials[t] : 0;
    sm[t] = v; __syncthreads();
    for (int off = 1; off < 256; off <<= 1){
        int add = (t >= off) ? sm[t-off] : 0;
        __syncthreads();
        sm[t] += add;
        __syncthreads();
    }
    if (t < nb) partials[t] = sm[t] - v;   // exclusive
}

__global__ void k_scan_final(const int* __restrict__ counts, int n,
                             const int* __restrict__ partials, int* __restrict__ rowptr){
    __shared__ int sm[256];
    int base = blockIdx.x * SCAN_TILE;
    int t = threadIdx.x;
    int v[4]; int s = 0;
    #pragma unroll
    for (int j = 0; j < 4; j++){
        int idx = base + t*4 + j;
        v[j] = (idx < n) ? counts[idx] : 0;
        s += v[j];
    }
    sm[t] = s; __syncthreads();
    for (int off = 1; off < 256; off <<= 1){
        int add = (t >= off) ? sm[t-off] : 0;
        __syncthreads();
        sm[t] += add;
        __syncthreads();
    }
    int excl = sm[t] - s + partials[blockIdx.x];
    #pragma unroll
    for (int j = 0; j < 4; j++){
        int idx = base + t*4 + j;
        if (idx < n) rowptr[idx] = excl;
        excl += v[j];
    }
    if (blockIdx.x == 0 && t == 0) rowptr[n] = NE;
}

__global__ void k_scatter(const int* __restrict__ dst, const int* __restrict__ src,
                          int* __restrict__ cursor, int* __restrict__ colsrc){
    int i = blockIdx.x * blockDim.x + threadIdx.x;
    if (i < NE){
        int p = atomicAdd(&cursor[dst[i]], 1);
        colsrc[p] = src[i];
    }
}

// ---------- helpers ----------
__device__ inline float dot4(float4 a, float4 b){
    return fmaf(a.x, b.x, fmaf(a.y, b.y, fmaf(a.z, b.z, a.w * b.w)));
}
__device__ inline float red16(float v){
    v += __shfl_xor(v, 1);
    v += __shfl_xor(v, 2);
    v += __shfl_xor(v, 4);
    v += __shfl_xor(v, 8);
    return v;
}

// ---------- GEMM + fused el/er epilogue, K-chunked, bf16 feat output ----------
// featb(N,128 bf16) = (relu?)(A(N,128)) @ W(128,128); el/er from fp32 accumulators.
template<int H, bool RELU>
__global__ __launch_bounds__(256) void k_gemm(const float* __restrict__ A,
                                              const float* __restrict__ W,
                                              const float* __restrict__ al,
                                              const float* __restrict__ ar,
                                              ushort_t* __restrict__ featb,
                                              float* __restrict__ el,
                                              float* __restrict__ er){
    __shared__ float Ws[32*128];   // 16 KB: K-chunk of W, layout [k][n]
    __shared__ float As[64*36];    // 9 KB: A chunk, stride 36 (16B-aligned rows)
    int t = threadIdx.x;
    long row0 = (long)blockIdx.x * 64;
    int g = t >> 4, c = t & 15;
    int r0 = g * 4;
    int lr = t >> 3, lc = (t & 7) * 4;
    float4 acc[4][2];
    #pragma unroll
    for (int i = 0; i < 4; i++){
        acc[i][0] = make_float4(0.f,0.f,0.f,0.f);
        acc[i][1] = make_float4(0.f,0.f,0.f,0.f);
    }
    for (int k0 = 0; k0 < 128; k0 += 32){
        __syncthreads();
        #pragma unroll
        for (int i = 0; i < 4; i++){
            int idx = t*4 + i*1024;
            *(float4*)&Ws[idx] = *(const float4*)&W[k0*FD + idx];
        }
        #pragma unroll
        for (int i = 0; i < 2; i++){
            int r = lr + i*32;
            float4 a = make_float4(0.f, 0.f, 0.f, 0.f);
            if (row0 + r < NN){
                a = *(const float4*)&A[(row0 + r)*FD + k0 + lc];
                if (RELU){
                    a.x = fmaxf(a.x, 0.f); a.y = fmaxf(a.y, 0.f);
                    a.z = fmaxf(a.z, 0.f); a.w = fmaxf(a.w, 0.f);
                }
            }
            *(float4*)&As[r*36 + lc] = a;
        }
        __syncthreads();
        #pragma unroll 4
        for (int k = 0; k < 32; k++){
            float4 w0 = *(const float4*)&Ws[k*FD + c*4];
            float4 w1 = *(const float4*)&Ws[k*FD + 64 + c*4];
            #pragma unroll
            for (int i = 0; i < 4; i++){
                float a = As[(r0+i)*36 + k];
                acc[i][0].x = fmaf(a, w0.x, acc[i][0].x);
                acc[i][0].y = fmaf(a, w0.y, acc[i][0].y);
                acc[i][0].z = fmaf(a, w0.z, acc[i][0].z);
                acc[i][0].w = fmaf(a, w0.w, acc[i][0].w);
                acc[i][1].x = fmaf(a, w1.x, acc[i][1].x);
                acc[i][1].y = fmaf(a, w1.y, acc[i][1].y);
                acc[i][1].z = fmaf(a, w1.z, acc[i][1].z);
                acc[i][1].w = fmaf(a, w1.w, acc[i][1].w);
            }
        }
    }
    // epilogue: bf16 feat stores + fused el/er (fp32)
    float4 alv0 = *(const float4*)&al[c*4];
    float4 alv1 = *(const float4*)&al[64 + c*4];
    float4 arv0 = *(const float4*)&ar[c*4];
    float4 arv1 = *(const float4*)&ar[64 + c*4];
    #pragma unroll
    for (int i = 0; i < 4; i++){
        long row = row0 + r0 + i;
        if (row < NN){
            uint2 p0 = make_uint2(pk(acc[i][0].x, acc[i][0].y), pk(acc[i][0].z, acc[i][0].w));
            uint2 p1 = make_uint2(pk(acc[i][1].x, acc[i][1].y), pk(acc[i][1].z, acc[i][1].w));
            *(uint2*)&featb[row*FD + c*4]      = p0;
            *(uint2*)&featb[row*FD + 64 + c*4] = p1;
        }
        if (H == 2){
            float pl0 = red16(dot4(acc[i][0], alv0));
            float pl1 = red16(dot4(acc[i][1], alv1));
            float pr0 = red16(dot4(acc[i][0], arv0));
            float pr1 = red16(dot4(acc[i][1], arv1));
            if (c == 0 && row < NN){
                el[row*2]   = pl0; el[row*2+1] = pl1;
                er[row*2]   = pr0; er[row*2+1] = pr1;
            }
        } else {
            float pl = red16(dot4(acc[i][0], alv0) + dot4(acc[i][1], alv1));
            float pr = red16(dot4(acc[i][0], arv0) + dot4(acc[i][1], arv1));
            if (c == 0 && row < NN){
                el[row] = pl; er[row] = pr;
            }
        }
    }
}

// ---------- per-relation aggregation core (inline softmax, bf16 gather) ----------
template<int H>
__device__ inline void agg_one(const int* __restrict__ rowptr, const int* __restrict__ colsrc,
                               const float* __restrict__ el, const float* __restrict__ er,
                               const ushort_t* __restrict__ featb, int node, int lane,
                               float& accx, float& accy, float& inv){
    int beg = rowptr[node], end = rowptr[node+1];
    float er0 = er[node*H];
    float er1 = (H == 2) ? er[node*H + 1] : 0.f;
    float s0 = 0.f, s1 = 0.f;
    accx = 0.f; accy = 0.f;
    for (int base = beg; base < end; base += 64){
        bool active = (base + lane) < end;
        int sv = active ? colsrc[base + lane] : 0;
        float a0 = 0.f, a1 = 0.f;
        if (active){
            if (H == 2){
                float2 e2 = *(const float2*)&el[sv*2];
                float e0 = e2.x + er0, e1 = e2.y + er1;
                e0 = (e0 > 0.f) ? e0 : 0.2f*e0;
                e1 = (e1 > 0.f) ? e1 : 0.2f*e1;
                a0 = __expf(e0); a1 = __expf(e1);
            } else {
                float e0 = el[sv] + er0;
                e0 = (e0 > 0.f) ? e0 : 0.2f*e0;
                a0 = __expf(e0);
            }
        }
        s0 += a0;
        if (H == 2) s1 += a1;
        int n = min(64, end - base);
        for (int j = 0; j < n; j++){
            int sj = __shfl(sv, j);
            float w0 = __shfl(a0, j);
            float w;
            if (H == 2){
                float w1 = __shfl(a1, j);
                w = (lane < 32) ? w0 : w1;
            } else {
                w = w0;
            }
            unsigned p = *(const unsigned*)&featb[(size_t)sj*FD + lane*2];
            float fx = __uint_as_float(p << 16);
            float fy = __uint_as_float(p & 0xffff0000u);
            accx = fmaf(w, fx, accx);
            accy = fmaf(w, fy, accy);
        }
    }
    #pragma unroll
    for (int off = 32; off > 0; off >>= 1){
        s0 += __shfl_xor(s0, off);
        if (H == 2) s1 += __shfl_xor(s1, off);
    }
    float i0 = (end > beg) ? 1.f/s0 : 0.f;
    float i1 = (H == 2 && end > beg) ? 1.f/s1 : 0.f;
    inv = (H == 2) ? ((lane < 32) ? i0 : i1) : i0;
}

// ---------- fused both-relations aggregation: one wave per dst node ----------
template<int H>
__global__ void k_agg2(const int* __restrict__ rowptr0, const int* __restrict__ colsrc0,
                       const int* __restrict__ rowptr1, const int* __restrict__ colsrc1,
                       const float* __restrict__ el0, const float* __restrict__ er0,
                       const float* __restrict__ el1, const float* __restrict__ er1,
                       const ushort_t* __restrict__ featb0, const ushort_t* __restrict__ featb1,
                       const float* __restrict__ bias0, const float* __restrict__ bias1,
                       float* __restrict__ out){
    int node = (blockIdx.x * blockDim.x + threadIdx.x) >> 6;
    int lane = threadIdx.x & 63;
    if (node >= NN) return;
    float a0x, a0y, inv0, a1x, a1y, inv1;
    agg_one<H>(rowptr0, colsrc0, el0, er0, featb0, node, lane, a0x, a0y, inv0);
    agg_one<H>(rowptr1, colsrc1, el1, er1, featb1, node, lane, a1x, a1y, inv1);
    float2 b0 = *(const float2*)&bias0[lane*2];
    float2 b1 = *(const float2*)&bias1[lane*2];
    float vx = 0.5f*(a0x*inv0 + a1x*inv1 + b0.x + b1.x);
    float vy = 0.5f*(a0y*inv0 + a1y*inv1 + b0.y + b1.y);
    float* o = &out[(size_t)node*FD + lane*2];
    o[0] = vx; o[1] = vy;
}

// ---------- launch ----------
extern "C" void kernel_launch(void* const* d_in, const int* in_sizes, int n_in,
                              void* d_out, int out_size, void* d_ws, size_t ws_size,
                              hipStream_t stream){
    const float* x   = (const float*)d_in[0];
    const float* W1  = (const float*)d_in[1];
    const float* al1 = (const float*)d_in[2];
    const float* ar1 = (const float*)d_in[3];
    const float* b1  = (const float*)d_in[4];
    const float* W2  = (const float*)d_in[5];
    const float* al2 = (const float*)d_in[6];
    const float* ar2 = (const float*)d_in[7];
    const float* b2  = (const float*)d_in[8];
    const int*   src = (const int*)d_in[9];
    const int*   dst = (const int*)d_in[10];
    float* out = (float*)d_out;

    size_t off = 0;
    auto carve = [&](size_t bytes) -> char* {
        char* p = (char*)d_ws + off;
        off += (bytes + 255) & ~(size_t)255;
        return p;
    };
    ushort_t* featb0 = (ushort_t*)carve((size_t)NN * FD * 2);
    ushort_t* featb1 = (ushort_t*)carve((size_t)NN * FD * 2);
    float* h1       = (float*)carve((size_t)NN * FD * 4);
    float* el0      = (float*)carve((size_t)NN * 2 * 4);
    float* er0      = (float*)carve((size_t)NN * 2 * 4);
    float* el1      = (float*)carve((size_t)NN * 2 * 4);
    float* er1      = (float*)carve((size_t)NN * 2 * 4);
    int*   rowptr0  = (int*)  carve((size_t)(NN + 1) * 4);
    int*   rowptr1  = (int*)  carve((size_t)(NN + 1) * 4);
    int*   colsrc0  = (int*)  carve((size_t)NE * 4);
    int*   colsrc1  = (int*)  carve((size_t)NE * 4);
    int*   counts   = (int*)  carve((size_t)NN * 4);
    int*   cursor   = (int*)  carve((size_t)NN * 4);
    int*   partials = (int*)  carve(1024);
    if (off > ws_size) return;

    const int EB = (NE + 255) / 256;
    const int NB = (NN + SCAN_TILE - 1) / SCAN_TILE;
    const int GB = (NN + 63) / 64;
    const int WB = NN / 4;   // 4 waves/block, 1 wave per node

    int* rowptrs[2] = {rowptr0, rowptr1};
    int* colsrcs[2] = {colsrc0, colsrc1};

    // build CSR per relation (shared by both layers); adjacency stores src ids
    for (int r = 0; r < 2; r++){
        const int* dstr = dst + (size_t)r * NE;
        const int* srcr = src + (size_t)r * NE;
        hipMemsetAsync(counts, 0, (size_t)NN * 4, stream);
        k_hist<<<EB, 256, 0, stream>>>(dstr, counts);
        k_scan_partial<<<NB, 256, 0, stream>>>(counts, NN, partials);
        k_scan_partials_excl<<<1, 256, 0, stream>>>(partials, NB);
        k_scan_final<<<NB, 256, 0, stream>>>(counts, NN, partials, rowptrs[r]);
        hipMemcpyAsync(cursor, rowptrs[r], (size_t)NN * 4, hipMemcpyDeviceToDevice, stream);
        k_scatter<<<EB, 256, 0, stream>>>(dstr, srcr, cursor, colsrcs[r]);
    }

    // layer 1: H=2, D=64
    k_gemm<2, false><<<GB, 256, 0, stream>>>(x, W1,                    al1,      ar1,      featb0, el0, er0);
    k_gemm<2, false><<<GB, 256, 0, stream>>>(x, W1 + (size_t)FD * FD,  al1 + FD, ar1 + FD, featb1, el1, er1);
    k_agg2<2><<<WB, 256, 0, stream>>>(rowptr0, colsrc0, rowptr1, colsrc1,
                                      el0, er0, el1, er1, featb0, featb1,
                                      b1, b1 + FD, h1);

    // layer 2: H=1, D=128 (relu folded into GEMM A-load)
    k_gemm<1, true><<<GB, 256, 0, stream>>>(h1, W2,                    al2,      ar2,      featb0, el0, er0);
    k_gemm<1, true><<<GB, 256, 0, stream>>>(h1, W2 + (size_t)FD * FD,  al2 + FD, ar2 + FD, featb1, el1, er1);
    k_agg2<1><<<WB, 256, 0, stream>>>(rowptr0, colsrc0, rowptr1, colsrc1,
                                      el0, er0, el1, er1, featb0, featb1,
                                      b2, b2 + FD, out);
}

// Round 5
// 578.940 us; speedup vs baseline: 2.7856x; 1.1283x over previous
//
#include <hip/hip_runtime.h>
#include <hip/hip_bf16.h>
#include <math.h>

#define NN 100000     // nodes
#define NE 800000     // edges per relation
#define FD 128        // feature dim

typedef unsigned short ushort_t;

// ---------- bf16 pack helpers (round-to-nearest-even) ----------
__device__ inline unsigned f2bf(float f){
    unsigned u = __float_as_uint(f);
    return (u + 0x7fffu + ((u >> 16) & 1u)) >> 16;
}
__device__ inline unsigned pk(float a, float b){
    return f2bf(a) | (f2bf(b) << 16);
}

// ---------- CSR build ----------
__global__ void k_hist(const int* __restrict__ dst, int* __restrict__ counts){
    int i = blockIdx.x * blockDim.x + threadIdx.x;
    if (i < NE) atomicAdd(&counts[dst[i]], 1);
}

#define SCAN_TILE 1024
__global__ void k_scan_partial(const int* __restrict__ counts, int n, int* __restrict__ partials){
    __shared__ int sm[256];
    int base = blockIdx.x * SCAN_TILE;
    int t = threadIdx.x;
    int s = 0;
    #pragma unroll
    for (int j = 0; j < 4; j++){
        int idx = base + t*4 + j;
        if (idx < n) s += counts[idx];
    }
    sm[t] = s; __syncthreads();
    for (int off = 128; off > 0; off >>= 1){
        if (t < off) sm[t] += sm[t+off];
        __syncthreads();
    }
    if (t == 0) partials[blockIdx.x] = sm[0];
}

__global__ void k_scan_partials_excl(int* partials, int nb){
    __shared__ int sm[256];
    int t = threadIdx.x;
    int v = (t < nb) ? partials[t] : 0;
    sm[t] = v; __syncthreads();
    for (int off = 1; off < 256; off <<= 1){
        int add = (t >= off) ? sm[t-off] : 0;
        __syncthreads();
        sm[t] += add;
        __syncthreads();
    }
    if (t < nb) partials[t] = sm[t] - v;   // exclusive
}

__global__ void k_scan_final(const int* __restrict__ counts, int n,
                             const int* __restrict__ partials, int* __restrict__ rowptr){
    __shared__ int sm[256];
    int base = blockIdx.x * SCAN_TILE;
    int t = threadIdx.x;
    int v[4]; int s = 0;
    #pragma unroll
    for (int j = 0; j < 4; j++){
        int idx = base + t*4 + j;
        v[j] = (idx < n) ? counts[idx] : 0;
        s += v[j];
    }
    sm[t] = s; __syncthreads();
    for (int off = 1; off < 256; off <<= 1){
        int add = (t >= off) ? sm[t-off] : 0;
        __syncthreads();
        sm[t] += add;
        __syncthreads();
    }
    int excl = sm[t] - s + partials[blockIdx.x];
    #pragma unroll
    for (int j = 0; j < 4; j++){
        int idx = base + t*4 + j;
        if (idx < n) rowptr[idx] = excl;
        excl += v[j];
    }
    if (blockIdx.x == 0 && t == 0) rowptr[n] = NE;
}

__global__ void k_scatter(const int* __restrict__ dst, const int* __restrict__ src,
                          int* __restrict__ cursor, int* __restrict__ colsrc){
    int i = blockIdx.x * blockDim.x + threadIdx.x;
    if (i < NE){
        int p = atomicAdd(&cursor[dst[i]], 1);
        colsrc[p] = src[i];
    }
}

// ---------- helpers ----------
__device__ inline float dot4(float4 a, float4 b){
    return fmaf(a.x, b.x, fmaf(a.y, b.y, fmaf(a.z, b.z, a.w * b.w)));
}
__device__ inline float red16(float v){
    v += __shfl_xor(v, 1);
    v += __shfl_xor(v, 2);
    v += __shfl_xor(v, 4);
    v += __shfl_xor(v, 8);
    return v;
}

// ---------- GEMM + fused el/er epilogue, K-chunked, bf16 feat output ----------
template<int H, bool RELU>
__global__ __launch_bounds__(256) void k_gemm(const float* __restrict__ A,
                                              const float* __restrict__ W,
                                              const float* __restrict__ al,
                                              const float* __restrict__ ar,
                                              ushort_t* __restrict__ featb,
                                              float* __restrict__ el,
                                              float* __restrict__ er){
    __shared__ float Ws[32*128];   // 16 KB: K-chunk of W, layout [k][n]
    __shared__ float As[64*36];    // 9 KB: A chunk, stride 36 (16B-aligned rows)
    int t = threadIdx.x;
    long row0 = (long)blockIdx.x * 64;
    int g = t >> 4, c = t & 15;
    int r0 = g * 4;
    int lr = t >> 3, lc = (t & 7) * 4;
    float4 acc[4][2];
    #pragma unroll
    for (int i = 0; i < 4; i++){
        acc[i][0] = make_float4(0.f,0.f,0.f,0.f);
        acc[i][1] = make_float4(0.f,0.f,0.f,0.f);
    }
    for (int k0 = 0; k0 < 128; k0 += 32){
        __syncthreads();
        #pragma unroll
        for (int i = 0; i < 4; i++){
            int idx = t*4 + i*1024;
            *(float4*)&Ws[idx] = *(const float4*)&W[k0*FD + idx];
        }
        #pragma unroll
        for (int i = 0; i < 2; i++){
            int r = lr + i*32;
            float4 a = make_float4(0.f, 0.f, 0.f, 0.f);
            if (row0 + r < NN){
                a = *(const float4*)&A[(row0 + r)*FD + k0 + lc];
                if (RELU){
                    a.x = fmaxf(a.x, 0.f); a.y = fmaxf(a.y, 0.f);
                    a.z = fmaxf(a.z, 0.f); a.w = fmaxf(a.w, 0.f);
                }
            }
            *(float4*)&As[r*36 + lc] = a;
        }
        __syncthreads();
        #pragma unroll 4
        for (int k = 0; k < 32; k++){
            float4 w0 = *(const float4*)&Ws[k*FD + c*4];
            float4 w1 = *(const float4*)&Ws[k*FD + 64 + c*4];
            #pragma unroll
            for (int i = 0; i < 4; i++){
                float a = As[(r0+i)*36 + k];
                acc[i][0].x = fmaf(a, w0.x, acc[i][0].x);
                acc[i][0].y = fmaf(a, w0.y, acc[i][0].y);
                acc[i][0].z = fmaf(a, w0.z, acc[i][0].z);
                acc[i][0].w = fmaf(a, w0.w, acc[i][0].w);
                acc[i][1].x = fmaf(a, w1.x, acc[i][1].x);
                acc[i][1].y = fmaf(a, w1.y, acc[i][1].y);
                acc[i][1].z = fmaf(a, w1.z, acc[i][1].z);
                acc[i][1].w = fmaf(a, w1.w, acc[i][1].w);
            }
        }
    }
    // epilogue: bf16 feat stores + fused el/er (fp32)
    float4 alv0 = *(const float4*)&al[c*4];
    float4 alv1 = *(const float4*)&al[64 + c*4];
    float4 arv0 = *(const float4*)&ar[c*4];
    float4 arv1 = *(const float4*)&ar[64 + c*4];
    #pragma unroll
    for (int i = 0; i < 4; i++){
        long row = row0 + r0 + i;
        if (row < NN){
            uint2 p0 = make_uint2(pk(acc[i][0].x, acc[i][0].y), pk(acc[i][0].z, acc[i][0].w));
            uint2 p1 = make_uint2(pk(acc[i][1].x, acc[i][1].y), pk(acc[i][1].z, acc[i][1].w));
            *(uint2*)&featb[row*FD + c*4]      = p0;
            *(uint2*)&featb[row*FD + 64 + c*4] = p1;
        }
        if (H == 2){
            float pl0 = red16(dot4(acc[i][0], alv0));
            float pl1 = red16(dot4(acc[i][1], alv1));
            float pr0 = red16(dot4(acc[i][0], arv0));
            float pr1 = red16(dot4(acc[i][1], arv1));
            if (c == 0 && row < NN){
                el[row*2]   = pl0; el[row*2+1] = pl1;
                er[row*2]   = pr0; er[row*2+1] = pr1;
            }
        } else {
            float pl = red16(dot4(acc[i][0], alv0) + dot4(acc[i][1], alv1));
            float pr = red16(dot4(acc[i][0], arv0) + dot4(acc[i][1], arv1));
            if (c == 0 && row < NN){
                el[row] = pl; er[row] = pr;
            }
        }
    }
}

// ---------- per-relation aggregation core: 16 lanes x 16B per gathered row ----------
// Wave = 4 groups of 16 lanes; each iteration gathers 4 edges' rows (4x dwordx4 in
// flight). lane sub = lane&15 covers feature cols [8*sub, 8*sub+8).
// H=2: sub<8 -> head0 (cols 0..63), sub>=8 -> head1 (cols 64..127).
template<int H>
__device__ inline void agg_one(const int* __restrict__ rowptr, const int* __restrict__ colsrc,
                               const float* __restrict__ el, const float* __restrict__ er,
                               const ushort_t* __restrict__ featb, int node, int lane,
                               float acc[8], float& inv){
    int beg = rowptr[node], end = rowptr[node+1];
    float er0 = er[node*H];
    float er1 = (H == 2) ? er[node*H + 1] : 0.f;
    int sub = lane & 15;
    int g   = lane >> 4;
    float s0 = 0.f, s1 = 0.f;
    for (int base = beg; base < end; base += 64){
        int nrem = end - base;
        bool active = lane < nrem;
        int sv = active ? colsrc[base + lane] : 0;
        float a0 = 0.f, a1 = 0.f;
        if (active){
            if (H == 2){
                float2 e2 = *(const float2*)&el[sv*2];
                float e0 = e2.x + er0, e1 = e2.y + er1;
                e0 = (e0 > 0.f) ? e0 : 0.2f*e0;
                e1 = (e1 > 0.f) ? e1 : 0.2f*e1;
                a0 = __expf(e0); a1 = __expf(e1);
            } else {
                float e0 = el[sv] + er0;
                e0 = (e0 > 0.f) ? e0 : 0.2f*e0;
                a0 = __expf(e0);
            }
        }
        s0 += a0;
        if (H == 2) s1 += a1;
        int nn = min(64, nrem);
        // 4 edges per iteration: group g handles slot j4+g (tail slots have weight 0)
        for (int j4 = 0; j4 < nn; j4 += 4){
            int slot = j4 + g;
            int sj = __shfl(sv, slot);
            float w;
            if (H == 2){
                float w0 = __shfl(a0, slot);
                float w1 = __shfl(a1, slot);
                w = (sub < 8) ? w0 : w1;
            } else {
                w = __shfl(a0, slot);
            }
            uint4 p = *(const uint4*)&featb[(size_t)sj*FD + sub*8];
            acc[0] = fmaf(w, __uint_as_float(p.x << 16),         acc[0]);
            acc[1] = fmaf(w, __uint_as_float(p.x & 0xffff0000u), acc[1]);
            acc[2] = fmaf(w, __uint_as_float(p.y << 16),         acc[2]);
            acc[3] = fmaf(w, __uint_as_float(p.y & 0xffff0000u), acc[3]);
            acc[4] = fmaf(w, __uint_as_float(p.z << 16),         acc[4]);
            acc[5] = fmaf(w, __uint_as_float(p.z & 0xffff0000u), acc[5]);
            acc[6] = fmaf(w, __uint_as_float(p.w << 16),         acc[6]);
            acc[7] = fmaf(w, __uint_as_float(p.w & 0xffff0000u), acc[7]);
        }
    }
    #pragma unroll
    for (int off = 32; off > 0; off >>= 1){
        s0 += __shfl_xor(s0, off);
        if (H == 2) s1 += __shfl_xor(s1, off);
    }
    float i0 = (end > beg) ? 1.f/s0 : 0.f;
    if (H == 2){
        float i1 = (end > beg) ? 1.f/s1 : 0.f;
        inv = (sub < 8) ? i0 : i1;
    } else {
        inv = i0;
    }
}

// ---------- fused both-relations aggregation: one wave per dst node ----------
template<int H>
__global__ void k_agg2(const int* __restrict__ rowptr0, const int* __restrict__ colsrc0,
                       const int* __restrict__ rowptr1, const int* __restrict__ colsrc1,
                       const float* __restrict__ el0, const float* __restrict__ er0,
                       const float* __restrict__ el1, const float* __restrict__ er1,
                       const ushort_t* __restrict__ featb0, const ushort_t* __restrict__ featb1,
                       const float* __restrict__ bias0, const float* __restrict__ bias1,
                       float* __restrict__ out){
    int node = (blockIdx.x * blockDim.x + threadIdx.x) >> 6;
    int lane = threadIdx.x & 63;
    if (node >= NN) return;
    float acc0[8] = {0.f,0.f,0.f,0.f,0.f,0.f,0.f,0.f};
    float acc1[8] = {0.f,0.f,0.f,0.f,0.f,0.f,0.f,0.f};
    float inv0, inv1;
    agg_one<H>(rowptr0, colsrc0, el0, er0, featb0, node, lane, acc0, inv0);
    agg_one<H>(rowptr1, colsrc1, el1, er1, featb1, node, lane, acc1, inv1);
    // reduce across the 4 groups (lane bits 4 and 5)
    #pragma unroll
    for (int i = 0; i < 8; i++){
        acc0[i] += __shfl_xor(acc0[i], 16);
        acc0[i] += __shfl_xor(acc0[i], 32);
        acc1[i] += __shfl_xor(acc1[i], 16);
        acc1[i] += __shfl_xor(acc1[i], 32);
    }
    if ((lane >> 4) == 0){
        int sub = lane;   // 0..15, covers cols [8*sub, 8*sub+8)
        float4 ba0 = *(const float4*)&bias0[sub*8];
        float4 bb0 = *(const float4*)&bias0[sub*8 + 4];
        float4 ba1 = *(const float4*)&bias1[sub*8];
        float4 bb1 = *(const float4*)&bias1[sub*8 + 4];
        float4 o0, o1;
        o0.x = 0.5f*(acc0[0]*inv0 + acc1[0]*inv1 + ba0.x + ba1.x);
        o0.y = 0.5f*(acc0[1]*inv0 + acc1[1]*inv1 + ba0.y + ba1.y);
        o0.z = 0.5f*(acc0[2]*inv0 + acc1[2]*inv1 + ba0.z + ba1.z);
        o0.w = 0.5f*(acc0[3]*inv0 + acc1[3]*inv1 + ba0.w + ba1.w);
        o1.x = 0.5f*(acc0[4]*inv0 + acc1[4]*inv1 + bb0.x + bb1.x);
        o1.y = 0.5f*(acc0[5]*inv0 + acc1[5]*inv1 + bb0.y + bb1.y);
        o1.z = 0.5f*(acc0[6]*inv0 + acc1[6]*inv1 + bb0.z + bb1.z);
        o1.w = 0.5f*(acc0[7]*inv0 + acc1[7]*inv1 + bb0.w + bb1.w);
        float* o = &out[(size_t)node*FD + sub*8];
        *(float4*)&o[0] = o0;
        *(float4*)&o[4] = o1;
    }
}

// ---------- launch ----------
extern "C" void kernel_launch(void* const* d_in, const int* in_sizes, int n_in,
                              void* d_out, int out_size, void* d_ws, size_t ws_size,
                              hipStream_t stream){
    const float* x   = (const float*)d_in[0];
    const float* W1  = (const float*)d_in[1];
    const float* al1 = (const float*)d_in[2];
    const float* ar1 = (const float*)d_in[3];
    const float* b1  = (const float*)d_in[4];
    const float* W2  = (const float*)d_in[5];
    const float* al2 = (const float*)d_in[6];
    const float* ar2 = (const float*)d_in[7];
    const float* b2  = (const float*)d_in[8];
    const int*   src = (const int*)d_in[9];
    const int*   dst = (const int*)d_in[10];
    float* out = (float*)d_out;

    size_t off = 0;
    auto carve = [&](size_t bytes) -> char* {
        char* p = (char*)d_ws + off;
        off += (bytes + 255) & ~(size_t)255;
        return p;
    };
    ushort_t* featb0 = (ushort_t*)carve((size_t)NN * FD * 2);
    ushort_t* featb1 = (ushort_t*)carve((size_t)NN * FD * 2);
    float* h1       = (float*)carve((size_t)NN * FD * 4);
    float* el0      = (float*)carve((size_t)NN * 2 * 4);
    float* er0      = (float*)carve((size_t)NN * 2 * 4);
    float* el1      = (float*)carve((size_t)NN * 2 * 4);
    float* er1      = (float*)carve((size_t)NN * 2 * 4);
    int*   rowptr0  = (int*)  carve((size_t)(NN + 1) * 4);
    int*   rowptr1  = (int*)  carve((size_t)(NN + 1) * 4);
    int*   colsrc0  = (int*)  carve((size_t)NE * 4);
    int*   colsrc1  = (int*)  carve((size_t)NE * 4);
    int*   counts   = (int*)  carve((size_t)NN * 4);
    int*   cursor   = (int*)  carve((size_t)NN * 4);
    int*   partials = (int*)  carve(1024);
    if (off > ws_size) return;

    const int EB = (NE + 255) / 256;
    const int NB = (NN + SCAN_TILE - 1) / SCAN_TILE;
    const int GB = (NN + 63) / 64;
    const int WB = NN / 4;   // 4 waves/block, 1 wave per node

    int* rowptrs[2] = {rowptr0, rowptr1};
    int* colsrcs[2] = {colsrc0, colsrc1};

    // build CSR per relation (shared by both layers); adjacency stores src ids
    for (int r = 0; r < 2; r++){
        const int* dstr = dst + (size_t)r * NE;
        const int* srcr = src + (size_t)r * NE;
        hipMemsetAsync(counts, 0, (size_t)NN * 4, stream);
        k_hist<<<EB, 256, 0, stream>>>(dstr, counts);
        k_scan_partial<<<NB, 256, 0, stream>>>(counts, NN, partials);
        k_scan_partials_excl<<<1, 256, 0, stream>>>(partials, NB);
        k_scan_final<<<NB, 256, 0, stream>>>(counts, NN, partials, rowptrs[r]);
        hipMemcpyAsync(cursor, rowptrs[r], (size_t)NN * 4, hipMemcpyDeviceToDevice, stream);
        k_scatter<<<EB, 256, 0, stream>>>(dstr, srcr, cursor, colsrcs[r]);
    }

    // layer 1: H=2, D=64
    k_gemm<2, false><<<GB, 256, 0, stream>>>(x, W1,                    al1,      ar1,      featb0, el0, er0);
    k_gemm<2, false><<<GB, 256, 0, stream>>>(x, W1 + (size_t)FD * FD,  al1 + FD, ar1 + FD, featb1, el1, er1);
    k_agg2<2><<<WB, 256, 0, stream>>>(rowptr0, colsrc0, rowptr1, colsrc1,
                                      el0, er0, el1, er1, featb0, featb1,
                                      b1, b1 + FD, h1);

    // layer 2: H=1, D=128 (relu folded into GEMM A-load)
    k_gemm<1, true><<<GB, 256, 0, stream>>>(h1, W2,                    al2,      ar2,      featb0, el0, er0);
    k_gemm<1, true><<<GB, 256, 0, stream>>>(h1, W2 + (size_t)FD * FD,  al2 + FD, ar2 + FD, featb1, el1, er1);
    k_agg2<1><<<WB, 256, 0, stream>>>(rowptr0, colsrc0, rowptr1, colsrc1,
                                      el0, er0, el1, er1, featb0, featb1,
                                      b2, b2 + FD, out);
}